// Round 1
// baseline (276.999 us; speedup 1.0000x reference)
//
#include <hip/hip_runtime.h>

#define TPB 256
#define NBLK 2048

__device__ __forceinline__ double rel_term(float x, float y) {
    float d = fabsf(x - y);
    float r = (y == 0.0f) ? d : d / y;
    return (double)r;
}

__global__ __launch_bounds__(TPB) void rdl_partial_kernel(
    const float4* __restrict__ x, const float4* __restrict__ y,
    double* __restrict__ partial, int nvec) {
    double acc = 0.0;
    int idx = blockIdx.x * TPB + threadIdx.x;
    int stride = gridDim.x * TPB;
    for (int i = idx; i < nvec; i += stride) {
        float4 xv = x[i];
        float4 yv = y[i];
        acc += rel_term(xv.x, yv.x);
        acc += rel_term(xv.y, yv.y);
        acc += rel_term(xv.z, yv.z);
        acc += rel_term(xv.w, yv.w);
    }
    // wave (64-lane) reduction
    for (int off = 32; off > 0; off >>= 1)
        acc += __shfl_down(acc, off, 64);
    __shared__ double smem[TPB / 64];
    int lane = threadIdx.x & 63;
    int wid  = threadIdx.x >> 6;
    if (lane == 0) smem[wid] = acc;
    __syncthreads();
    if (threadIdx.x == 0) {
        double s = 0.0;
        #pragma unroll
        for (int w = 0; w < TPB / 64; ++w) s += smem[w];
        partial[blockIdx.x] = s;
    }
}

__global__ __launch_bounds__(TPB) void rdl_final_kernel(
    const double* __restrict__ partial, float* __restrict__ out,
    int nblocks, double invN) {
    double acc = 0.0;
    for (int i = threadIdx.x; i < nblocks; i += TPB)
        acc += partial[i];
    for (int off = 32; off > 0; off >>= 1)
        acc += __shfl_down(acc, off, 64);
    __shared__ double smem[TPB / 64];
    int lane = threadIdx.x & 63;
    int wid  = threadIdx.x >> 6;
    if (lane == 0) smem[wid] = acc;
    __syncthreads();
    if (threadIdx.x == 0) {
        double s = 0.0;
        #pragma unroll
        for (int w = 0; w < TPB / 64; ++w) s += smem[w];
        out[0] = (float)(s * invN);
    }
}

extern "C" void kernel_launch(void* const* d_in, const int* in_sizes, int n_in,
                              void* d_out, int out_size, void* d_ws, size_t ws_size,
                              hipStream_t stream) {
    const float* x = (const float*)d_in[0];
    const float* y = (const float*)d_in[1];
    int n = in_sizes[0];          // 33554432, divisible by 4
    int nvec = n / 4;
    double* partial = (double*)d_ws;   // NBLK * 8 = 16 KB scratch

    rdl_partial_kernel<<<NBLK, TPB, 0, stream>>>(
        (const float4*)x, (const float4*)y, partial, nvec);
    rdl_final_kernel<<<1, TPB, 0, stream>>>(
        partial, (float*)d_out, NBLK, 1.0 / (double)n);
}